// Round 5
// baseline (47.941 us; speedup 1.0000x reference)
//
#include <hip/hip_runtime.h>

// RPQWeight gather, LDS-staged codebook, single-round schedule:
//   indices:   (H=32, C=16384) int32 in [0,256)
//   codebooks: (H=32, NC=256, D=128) float32
//   out[c, h*128+d] = codebooks[h, indices[h,c], d]   -> (16384, 4096) f32
//
// R5: R4 structure (256 blocks = 1/CU, one h + 2048 rows per block,
// 128 KiB codebook slice + 8 KiB indices in LDS, zero global reads in
// steady state) + three refinements:
//   1. two-phase prologue: all 10 global loads issued to regs before any
//      LDS write -> single HBM latency instead of a chained prologue
//   2. all store offsets in u32 (output = 2^28 B): sgpr-base + voffset
//      addressing, no 64-bit carry chain per store
//   3. unroll 16 for deeper store-issue ILP

#define RPQ_H  32
#define RPQ_C  16384
#define RPQ_D  128
#define RPQ_NC 256

#define BLOCK        1024
#define CBLK_PER_H   8
#define ROWS_PER_BLK (RPQ_C / CBLK_PER_H)          // 2048
#define GRID         (RPQ_H * CBLK_PER_H)          // 256 = #CUs

#define CB_F4_PER_H   (RPQ_NC * RPQ_D / 4)         // 8192 float4 = 128 KiB
#define LDS_CB_BYTES  (CB_F4_PER_H * 16)           // 131072
#define LDS_IDX_BYTES (ROWS_PER_BLK * 4)           // 8192
#define LDS_BYTES     (LDS_CB_BYTES + LDS_IDX_BYTES)  // 139264 <= 160 KiB

#define ROW_F4       (RPQ_H * RPQ_D / 4)           // 1024 float4 per out row
#define ITERS        (ROWS_PER_BLK / 32)           // 64

typedef float f4 __attribute__((ext_vector_type(4)));

__global__ __launch_bounds__(BLOCK) void rpq_lds_kernel(
        const int* __restrict__ indices,
        const float* __restrict__ codebooks,
        float* __restrict__ out) {
    extern __shared__ char smem[];
    f4*  lds_cb  = reinterpret_cast<f4*>(smem);
    int* lds_idx = reinterpret_cast<int*>(smem + LDS_CB_BYTES);

    const unsigned bid    = blockIdx.x;
    const unsigned h      = bid >> 3;          // 8 blocks per h
    const unsigned cblk   = bid & 7u;
    const unsigned c_base = cblk * ROWS_PER_BLK;
    const unsigned tid    = threadIdx.x;

    // --- Prologue, phase 1: issue ALL global loads (independent) ---
    const f4* cb4 = reinterpret_cast<const f4*>(codebooks) + (size_t)h * CB_F4_PER_H;
    f4 stage[8];
#pragma unroll
    for (int k = 0; k < 8; ++k)
        stage[k] = cb4[tid + k * BLOCK];
    const int i0 = indices[h * RPQ_C + c_base + tid];
    const int i1 = indices[h * RPQ_C + c_base + tid + BLOCK];

    // --- Prologue, phase 2: LDS writes ---
#pragma unroll
    for (int k = 0; k < 8; ++k)
        lds_cb[tid + k * BLOCK] = stage[k];
    lds_idx[tid]         = i0;
    lds_idx[tid + BLOCK] = i1;
    __syncthreads();

    // --- Main loop: thread -> (row r0 + 32*it, float4 column d4 of h) ---
    const unsigned d4 = tid & 31u;             // float4 within the 128-f slice
    const unsigned r0 = tid >> 5;              // 0..31
    // All output offsets fit in u32 (2^26 f4 elements total).
    const unsigned o_off = (c_base + r0) * (unsigned)ROW_F4
                         + h * (RPQ_D / 4) + d4;
    f4* __restrict__ o = reinterpret_cast<f4*>(out) + o_off;

#pragma unroll 16
    for (unsigned it = 0; it < ITERS; ++it) {
        const int idx = lds_idx[it * 32u + r0];            // LDS broadcast
        const f4  v   = lds_cb[(unsigned)idx * 32u + d4];  // conflict-free
        o[it * (32u * (unsigned)ROW_F4)] = v;              // coalesced
    }
}

extern "C" void kernel_launch(void* const* d_in, const int* in_sizes, int n_in,
                              void* d_out, int out_size, void* d_ws, size_t ws_size,
                              hipStream_t stream) {
    const int*   indices   = (const int*)d_in[0];
    const float* codebooks = (const float*)d_in[1];
    float*       out       = (float*)d_out;

    // >64 KiB dynamic LDS needs explicit opt-in (host-side attr, not a
    // stream op; graph-capture-safe, idempotent, deterministic).
    hipFuncSetAttribute((const void*)rpq_lds_kernel,
                        hipFuncAttributeMaxDynamicSharedMemorySize, LDS_BYTES);

    rpq_lds_kernel<<<GRID, BLOCK, LDS_BYTES, stream>>>(indices, codebooks, out);
}